// Round 9
// baseline (196.871 us; speedup 1.0000x reference)
//
#include <hip/hip_runtime.h>
#include <hip/hip_cooperative_groups.h>
namespace cg = cooperative_groups;

// RoIAlign (aligned-corner variant), fixed shape:
//   features: (N=2, C=256, H=200, W=304) f32 NCHW, rois: (R,5) f32, scale f32
//   out: (R, 256, 7, 7) f32
// Fused cooperative kernel: phase 1 NCHW f32 -> NHWC f16 into ws, grid.sync,
// phase 2 coalesced gather (R8-proven logic). Fallback: two-kernel path.
#define C_ 256
#define H_ 200
#define W_ 304
#define AH 7
#define AW 7
#define KK 49
#define ROWU 131  // u32/row; stride 131 = 3 mod 32 -> conflict-free copy-out
#define BUFW 6419 // KK*ROWU u32 (25676 B); phase 1 uses first 128*34=4352

typedef float f32x4 __attribute__((ext_vector_type(4)));

__device__ __forceinline__ float h2f(unsigned short s) {
    _Float16 h; __builtin_memcpy(&h, &s, 2); return (float)h;
}
__device__ __forceinline__ unsigned short f2h(float f) {
    _Float16 h = (_Float16)f; unsigned short s; __builtin_memcpy(&s, &h, 2); return s;
}

// ---------- shared device helpers ----------
__device__ __forceinline__ void samp(
    const unsigned short* __restrict__ fb, int k,
    float y1, float x1, float bin_h, float bin_w, int c4, float* o) {
    const int ph = k / AW;
    const int pw = k - ph * AW;
    const float h  = y1 + (float)ph * bin_h;
    const float w  = x1 + (float)pw * bin_w;
    const float hs = fminf(fmaxf(floorf(h), 0.0f), (float)(H_ - 2));
    const float ws = fminf(fmaxf(floorf(w), 0.0f), (float)(W_ - 2));
    const float dh = h - hs;
    const float dw = w - ws;
    const int   yi = (int)hs;
    const int   xi = (int)ws;
    const bool  valid = (h >= 0.0f) && (h < (float)H_) &&
                        (w >= 0.0f) && (w < (float)W_);
    const unsigned short* p = fb + ((size_t)yi * W_ + xi) * C_ + c4;
    const ushort4 a00 = *(const ushort4*)p;
    const ushort4 a01 = *(const ushort4*)(p + C_);
    const ushort4 a10 = *(const ushort4*)(p + (size_t)W_ * C_);
    const ushort4 a11 = *(const ushort4*)(p + (size_t)W_ * C_ + C_);
    const float w00 = (1.0f - dh) * (1.0f - dw);
    const float w01 = (1.0f - dh) * dw;
    const float w10 = dh * (1.0f - dw);
    const float w11 = dh * dw;
    o[0] = h2f(a00.x) * w00 + h2f(a01.x) * w01 + h2f(a10.x) * w10 + h2f(a11.x) * w11;
    o[1] = h2f(a00.y) * w00 + h2f(a01.y) * w01 + h2f(a10.y) * w10 + h2f(a11.y) * w11;
    o[2] = h2f(a00.z) * w00 + h2f(a01.z) * w01 + h2f(a10.z) * w10 + h2f(a11.z) * w11;
    o[3] = h2f(a00.w) * w00 + h2f(a01.w) * w01 + h2f(a10.w) * w10 + h2f(a11.w) * w11;
    if (!valid) { o[0] = 0.0f; o[1] = 0.0f; o[2] = 0.0f; o[3] = 0.0f; }
}

// ---------- Fused cooperative kernel ----------
__global__ __launch_bounds__(512) void roialign_fused(
    const float* __restrict__ feat, unsigned short* __restrict__ tf,
    const float* __restrict__ rois, const float* __restrict__ scale_ptr,
    float* __restrict__ out, int nblocks, int R, int ntile) {
    __shared__ unsigned int buf[BUFW];
    const int bid = blockIdx.x;
    const int HW = H_ * W_;

    // ---- Phase 1: NCHW f32 -> NHWC f16 (one 64px x 128ch tile per iter) ----
    for (int tile = bid; tile < ntile; tile += nblocks) {
        const int px   = tile % 950;
        const int rest = tile / 950;
        const int p0 = px * 64;
        const int c0 = (rest & 1) * 128;
        const int n  = rest >> 1;
        const float* inb = feat + (size_t)n * C_ * HW;
        unsigned short* outb = tf + (size_t)n * HW * C_;
        __syncthreads();  // protect buf reuse across iterations
        {   // load: 512 thr, each 4 float4 (f32->f16 packed into LDS)
            const int q  = threadIdx.x & 15;   // pixel quad
            const int r0 = threadIdx.x >> 4;   // 0..31
            #pragma unroll
            for (int i = 0; i < 4; ++i) {
                const int c = r0 + 32 * i;     // 0..127
                const f32x4 v = __builtin_nontemporal_load(
                    (const f32x4*)&inb[(size_t)(c0 + c) * HW + p0 + 4 * q]);
                const unsigned int ulo = (unsigned)f2h(v.x) | ((unsigned)f2h(v.y) << 16);
                const unsigned int uhi = (unsigned)f2h(v.z) | ((unsigned)f2h(v.w) << 16);
                *(uint2*)&buf[c * 34 + 2 * q] = make_uint2(ulo, uhi);
            }
        }
        __syncthreads();
        {   // store: 512 thr, each one (pixel-pair, channel-octet)
            const int pp = threadIdx.x & 31;   // pixel-pair 0..31
            const int cq = threadIdx.x >> 5;   // channel octet 0..15
            unsigned int u[8];
            #pragma unroll
            for (int jj = 0; jj < 8; ++jj) u[jj] = buf[(8 * cq + jj) * 34 + pp];
            unsigned int pe[4], po[4];
            #pragma unroll
            for (int k = 0; k < 4; ++k) {
                pe[k] = (u[2 * k] & 0xFFFFu) | (u[2 * k + 1] << 16);
                po[k] = (u[2 * k] >> 16) | (u[2 * k + 1] & 0xFFFF0000u);
            }
            unsigned short* oA = &outb[(size_t)(p0 + 2 * pp) * C_ + c0 + 8 * cq];
            unsigned short* oB = oA + C_;
            *(uint4*)oA = make_uint4(pe[0], pe[1], pe[2], pe[3]);
            *(uint4*)oB = make_uint4(po[0], po[1], po[2], po[3]);
        }
    }

    __threadfence();           // device-scope release (cross-XCD visibility)
    cg::this_grid().sync();    // grid-wide barrier

    // ---- Phase 2: gather from NHWC f16 (R8-proven) ----
    const float scale = scale_ptr[0];
    const int wave = threadIdx.x >> 6;
    const int lane = threadIdx.x & 63;
    const int c4   = lane * 4;

    for (int r = bid; r < R; r += nblocks) {
        const float* roi = rois + (size_t)r * 5;
        const int   b  = (int)roi[0];
        const float x1 = roi[1] * scale;
        const float y1 = roi[2] * scale;
        const float x2 = roi[3] * scale;
        const float y2 = roi[4] * scale;
        const float roi_w = fmaxf(x2 - x1 + 1.0f, 0.0f);
        const float roi_h = fmaxf(y2 - y1 + 1.0f, 0.0f);
        const float bin_h = roi_h / (float)(AH - 1);
        const float bin_w = roi_w / (float)(AW - 1);
        const unsigned short* fb = tf + (size_t)b * (H_ * W_) * C_;

        __syncthreads();  // protect buf reuse across ROI iterations
        #pragma unroll 2
        for (int k = wave; k < KK; k += 8) {
            float v[4];
            samp(fb, k, y1, x1, bin_h, bin_w, c4, v);
            const unsigned int u0 = (unsigned)f2h(v[0]) | ((unsigned)f2h(v[1]) << 16);
            const unsigned int u1 = (unsigned)f2h(v[2]) | ((unsigned)f2h(v[3]) << 16);
            buf[k * ROWU + 2 * lane]     = u0;
            buf[k * ROWU + 2 * lane + 1] = u1;
        }
        __syncthreads();

        float* ob = out + (size_t)r * (C_ * KK);
        #pragma unroll
        for (int i = 0; i < 25; ++i) {
            const int f = threadIdx.x + 512 * i;
            if (i < 24 || f < C_ * KK) {
                const int c = f / KK;
                const int k = f - c * KK;
                const unsigned int u = buf[k * ROWU + (c >> 1)];
                const unsigned short hv = (c & 1) ? (unsigned short)(u >> 16)
                                                  : (unsigned short)(u & 0xFFFFu);
                __builtin_nontemporal_store(h2f(hv), &ob[f]);
            }
        }
    }
}

// ---------- Fallback path: two kernels (R8, proven 79us) ----------
__global__ __launch_bounds__(256) void transpose_nchw_nhwc_f16(
    const float* __restrict__ in, unsigned short* __restrict__ out) {
    __shared__ unsigned int tile[128][34];
    const int HW = H_ * W_;
    const int n  = blockIdx.z;
    const int p0 = blockIdx.x * 64;
    const int c0 = blockIdx.y * 128;
    const float* inb = in + (size_t)n * C_ * HW;
    unsigned short* outb = out + (size_t)n * HW * C_;
    {
        const int q  = threadIdx.x & 15;
        const int r0 = threadIdx.x >> 4;
        #pragma unroll
        for (int i = 0; i < 8; ++i) {
            const int c = r0 + 16 * i;
            const f32x4 v = __builtin_nontemporal_load(
                (const f32x4*)&inb[(size_t)(c0 + c) * HW + p0 + 4 * q]);
            const unsigned int ulo = (unsigned)f2h(v.x) | ((unsigned)f2h(v.y) << 16);
            const unsigned int uhi = (unsigned)f2h(v.z) | ((unsigned)f2h(v.w) << 16);
            *(uint2*)&tile[c][2 * q] = make_uint2(ulo, uhi);
        }
    }
    __syncthreads();
    {
        const int pp0 = threadIdx.x & 15;
        const int cq  = threadIdx.x >> 4;
        #pragma unroll
        for (int i = 0; i < 2; ++i) {
            const int pp = pp0 + 16 * i;
            unsigned int u[8];
            #pragma unroll
            for (int jj = 0; jj < 8; ++jj) u[jj] = tile[8 * cq + jj][pp];
            unsigned int pe[4], po[4];
            #pragma unroll
            for (int k = 0; k < 4; ++k) {
                pe[k] = (u[2 * k] & 0xFFFFu) | (u[2 * k + 1] << 16);
                po[k] = (u[2 * k] >> 16) | (u[2 * k + 1] & 0xFFFF0000u);
            }
            unsigned short* oA = &outb[(size_t)(p0 + 2 * pp) * C_ + c0 + 8 * cq];
            unsigned short* oB = oA + C_;
            *(uint4*)oA = make_uint4(pe[0], pe[1], pe[2], pe[3]);
            *(uint4*)oB = make_uint4(po[0], po[1], po[2], po[3]);
        }
    }
}

__global__ __launch_bounds__(512) void roialign_nhwc_f16(
    const unsigned short* __restrict__ tf, const float* __restrict__ rois,
    const float* __restrict__ scale_ptr, float* __restrict__ out) {
    __shared__ unsigned int shu[KK * ROWU];
    const int r    = blockIdx.x;
    const int wave = threadIdx.x >> 6;
    const int lane = threadIdx.x & 63;
    const int c4   = lane * 4;
    const float scale = scale_ptr[0];
    const float* roi = rois + (size_t)r * 5;
    const int   b  = (int)roi[0];
    const float x1 = roi[1] * scale;
    const float y1 = roi[2] * scale;
    const float x2 = roi[3] * scale;
    const float y2 = roi[4] * scale;
    const float roi_w = fmaxf(x2 - x1 + 1.0f, 0.0f);
    const float roi_h = fmaxf(y2 - y1 + 1.0f, 0.0f);
    const float bin_h = roi_h / (float)(AH - 1);
    const float bin_w = roi_w / (float)(AW - 1);
    const unsigned short* fb = tf + (size_t)b * (H_ * W_) * C_;

    #pragma unroll 2
    for (int k = wave; k < KK; k += 8) {
        float v[4];
        samp(fb, k, y1, x1, bin_h, bin_w, c4, v);
        const unsigned int u0 = (unsigned)f2h(v[0]) | ((unsigned)f2h(v[1]) << 16);
        const unsigned int u1 = (unsigned)f2h(v[2]) | ((unsigned)f2h(v[3]) << 16);
        shu[k * ROWU + 2 * lane]     = u0;
        shu[k * ROWU + 2 * lane + 1] = u1;
    }
    __syncthreads();
    float* ob = out + (size_t)r * (C_ * KK);
    #pragma unroll
    for (int i = 0; i < 25; ++i) {
        const int f = threadIdx.x + 512 * i;
        if (i < 24 || f < C_ * KK) {
            const int c = f / KK;
            const int k = f - c * KK;
            const unsigned int u = shu[k * ROWU + (c >> 1)];
            const unsigned short hv = (c & 1) ? (unsigned short)(u >> 16)
                                              : (unsigned short)(u & 0xFFFFu);
            __builtin_nontemporal_store(h2f(hv), &ob[f]);
        }
    }
}

__global__ __launch_bounds__(256) void roialign_nchw(
    const float* __restrict__ feat, const float* __restrict__ rois,
    const float* __restrict__ scale_ptr, float* __restrict__ out) {
    __shared__ float sout[C_ * KK];
    const int r = blockIdx.x;
    const int c = threadIdx.x;
    const float scale = scale_ptr[0];
    const float* roi = rois + (size_t)r * 5;
    const int   b  = (int)roi[0];
    const float x1 = roi[1] * scale;
    const float y1 = roi[2] * scale;
    const float x2 = roi[3] * scale;
    const float y2 = roi[4] * scale;
    const float roi_w = fmaxf(x2 - x1 + 1.0f, 0.0f);
    const float roi_h = fmaxf(y2 - y1 + 1.0f, 0.0f);
    const float bin_h = roi_h / (float)(AH - 1);
    const float bin_w = roi_w / (float)(AW - 1);
    const float* fb = feat + ((size_t)b * C_ + c) * (H_ * W_);
    for (int ph = 0; ph < AH; ++ph) {
        const float h  = y1 + (float)ph * bin_h;
        const float hs = fminf(fmaxf(floorf(h), 0.0f), (float)(H_ - 2));
        const float dh = h - hs;
        const int   yi = (int)hs;
        const bool  vh = (h >= 0.0f) && (h < (float)H_);
        #pragma unroll
        for (int pw = 0; pw < AW; ++pw) {
            const float w  = x1 + (float)pw * bin_w;
            const float ws = fminf(fmaxf(floorf(w), 0.0f), (float)(W_ - 2));
            const float dw = w - ws;
            const int   xi = (int)ws;
            const bool  valid = vh && (w >= 0.0f) && (w < (float)W_);
            const float v00 = fb[(size_t)yi * W_ + xi];
            const float v01 = fb[(size_t)yi * W_ + xi + 1];
            const float v10 = fb[(size_t)(yi + 1) * W_ + xi];
            const float v11 = fb[(size_t)(yi + 1) * W_ + xi + 1];
            float val = v00 * (1.0f - dh) * (1.0f - dw)
                      + v01 * (1.0f - dh) * dw
                      + v10 * dh * (1.0f - dw)
                      + v11 * dh * dw;
            sout[c * KK + ph * AW + pw] = valid ? val : 0.0f;
        }
    }
    __syncthreads();
    float* ob = out + (size_t)r * C_ * KK;
    #pragma unroll 4
    for (int i = threadIdx.x; i < C_ * KK; i += 256) ob[i] = sout[i];
}

extern "C" void kernel_launch(void* const* d_in, const int* in_sizes, int n_in,
                              void* d_out, int out_size, void* d_ws, size_t ws_size,
                              hipStream_t stream) {
    const float* feat  = (const float*)d_in[0];
    const float* rois  = (const float*)d_in[1];
    const float* scale = (const float*)d_in[2];
    float* out = (float*)d_out;

    const int R = in_sizes[1] / 5;                 // 2000
    const int N = in_sizes[0] / (C_ * H_ * W_);    // 2
    const size_t need = (size_t)N * C_ * H_ * W_ * sizeof(unsigned short);

    if (ws_size >= need) {
        unsigned short* tf = (unsigned short*)d_ws;
        // --- try fused cooperative launch ---
        int maxb = 0;
        hipError_t qe = hipOccupancyMaxActiveBlocksPerMultiprocessor(
            &maxb, (const void*)roialign_fused, 512, 0);
        int G = (qe == hipSuccess) ? maxb * 256 : 0;
        if (G > 1024) G = 1024;
        if (G >= 256) {
            int ntile = 950 * 2 * N;  // (HW/64) * (C/128) * N
            void* args[] = { (void*)&feat, (void*)&tf, (void*)&rois,
                             (void*)&scale, (void*)&out,
                             (void*)&G, (void*)&R, (void*)&ntile };
            hipError_t le = hipLaunchCooperativeKernel(
                (const void*)roialign_fused, dim3(G), dim3(512), args, 0, stream);
            if (le == hipSuccess) return;
        }
        // --- fallback: proven two-kernel path ---
        dim3 tb(256);
        dim3 tg((H_ * W_) / 64, C_ / 128, N);
        hipLaunchKernelGGL(transpose_nchw_nhwc_f16, tg, tb, 0, stream, feat, tf);
        hipLaunchKernelGGL(roialign_nhwc_f16, dim3(R), dim3(512), 0, stream,
                           tf, rois, scale, out);
    } else {
        hipLaunchKernelGGL(roialign_nchw, dim3(R), dim3(256), 0, stream,
                           feat, rois, scale, out);
    }
}

// Round 10
// 84.111 us; speedup vs baseline: 2.3406x; 2.3406x over previous
//
#include <hip/hip_runtime.h>

// RoIAlign (aligned-corner variant), fixed shape:
//   features: (N=2, C=256, H=200, W=304) f32 NCHW, rois: (R,5) f32, scale f32
//   out: (R, 256, 7, 7) f32
// Pipeline: NCHW f32 -> NHWC f16 transpose (HBM roofline), then gather with
// 1KB contiguous row-loads + shfl_xor x-exchange + f16 LDS staging.
#define C_ 256
#define H_ 200
#define W_ 304
#define AH 7
#define AW 7
#define KK 49
#define ROWU 131  // u32/row; stride 131 = 3 mod 32 -> conflict-free copy-out

typedef float f32x4 __attribute__((ext_vector_type(4)));

__device__ __forceinline__ float h2f(unsigned short s) {
    _Float16 h; __builtin_memcpy(&h, &s, 2); return (float)h;
}
__device__ __forceinline__ unsigned short f2h(float f) {
    _Float16 h = (_Float16)f; unsigned short s; __builtin_memcpy(&s, &h, 2); return s;
}

// ---------- Kernel 1: NCHW f32 -> NHWC f16 (HBM roofline; R8 unchanged) ----------
__global__ __launch_bounds__(256) void transpose_nchw_nhwc_f16(
    const float* __restrict__ in, unsigned short* __restrict__ out) {
    __shared__ unsigned int tile[128][34];  // [ch][px-pair], 17408 B
    const int HW = H_ * W_;
    const int n  = blockIdx.z;
    const int p0 = blockIdx.x * 64;
    const int c0 = blockIdx.y * 128;
    const float* inb = in + (size_t)n * C_ * HW;
    unsigned short* outb = out + (size_t)n * HW * C_;

    {   // load: lanes walk pixel-quads, convert f32->f16 before LDS
        const int q  = threadIdx.x & 15;
        const int r0 = threadIdx.x >> 4;
        #pragma unroll
        for (int i = 0; i < 8; ++i) {
            const int c = r0 + 16 * i;
            const f32x4 v = __builtin_nontemporal_load(
                (const f32x4*)&inb[(size_t)(c0 + c) * HW + p0 + 4 * q]);
            const unsigned int ulo = (unsigned)f2h(v.x) | ((unsigned)f2h(v.y) << 16);
            const unsigned int uhi = (unsigned)f2h(v.z) | ((unsigned)f2h(v.w) << 16);
            *(uint2*)&tile[c][2 * q] = make_uint2(ulo, uhi);
        }
    }
    __syncthreads();
    {   // store: repack pixel-pairs -> channel-contiguous ushort8 (16B/lane)
        const int pp0 = threadIdx.x & 15;
        const int cq  = threadIdx.x >> 4;
        #pragma unroll
        for (int i = 0; i < 2; ++i) {
            const int pp = pp0 + 16 * i;
            unsigned int u[8];
            #pragma unroll
            for (int jj = 0; jj < 8; ++jj) u[jj] = tile[8 * cq + jj][pp];
            unsigned int pe[4], po[4];
            #pragma unroll
            for (int k = 0; k < 4; ++k) {
                pe[k] = (u[2 * k] & 0xFFFFu) | (u[2 * k + 1] << 16);
                po[k] = (u[2 * k] >> 16) | (u[2 * k + 1] & 0xFFFF0000u);
            }
            unsigned short* oA = &outb[(size_t)(p0 + 2 * pp) * C_ + c0 + 8 * cq];
            unsigned short* oB = oA + C_;
            *(uint4*)oA = make_uint4(pe[0], pe[1], pe[2], pe[3]);
            *(uint4*)oB = make_uint4(po[0], po[1], po[2], po[3]);
        }
    }
}

// ---------- Kernel 2: gather, 1KB row-loads + shfl x-exchange ----------
// 512 thr = 8 waves per ROI. Wave w: 7 CONSECUTIVE points k = (49w>>3)+j
// (small benign overlaps; all 0..48 covered; spans <=2 feature rows -> L1 reuse).
// Per point: two 1KB wave-loads (rows yi, yi+1 covering pixels xi,xi+1).
// Lane L: 8 channels of one x. y-interp in f32, pack f16 pairs, shfl_xor(32)
// brings partner x; lanes 0-31 x-interp and write LDS row k (R8 layout).
__global__ __launch_bounds__(512) void roialign_nhwc_f16(
    const unsigned short* __restrict__ tf, const float* __restrict__ rois,
    const float* __restrict__ scale_ptr, float* __restrict__ out) {
    __shared__ unsigned int shu[KK * ROWU];  // 25676 B -> 4 blocks/CU (thread-cap)
    const int r    = blockIdx.x;
    const int wave = threadIdx.x >> 6;
    const int lane = threadIdx.x & 63;

    const float scale = scale_ptr[0];
    const float* roi = rois + (size_t)r * 5;
    const int   b  = (int)roi[0];
    const float x1 = roi[1] * scale;
    const float y1 = roi[2] * scale;
    const float x2 = roi[3] * scale;
    const float y2 = roi[4] * scale;
    const float roi_w = fmaxf(x2 - x1 + 1.0f, 0.0f);
    const float roi_h = fmaxf(y2 - y1 + 1.0f, 0.0f);
    const float bin_h = roi_h / (float)(AH - 1);
    const float bin_w = roi_w / (float)(AW - 1);
    const unsigned short* fb = tf + (size_t)b * (H_ * W_) * C_;

    const int base = (49 * wave) >> 3;  // 0,6,12,18,24,30,36,42
    #pragma unroll
    for (int j = 0; j < 7; ++j) {
        const int k  = base + j;        // <= 48
        const int ph = k / AW;
        const int pw = k - ph * AW;
        const float h  = y1 + (float)ph * bin_h;
        const float w  = x1 + (float)pw * bin_w;
        const float hs = fminf(fmaxf(floorf(h), 0.0f), (float)(H_ - 2));
        const float ws = fminf(fmaxf(floorf(w), 0.0f), (float)(W_ - 2));
        const float dh = h - hs;
        const float dw = w - ws;
        const int   yi = (int)hs;
        const int   xi = (int)ws;
        const bool  valid = (h >= 0.0f) && (h < (float)H_) &&
                            (w >= 0.0f) && (w < (float)W_);
        // 1KB rows: pixels (yi,xi),(yi,xi+1) are contiguous 512B each
        const uint4* rowA = (const uint4*)(fb + (((size_t)yi * W_ + xi) << 8));
        const uint4* rowB = rowA + ((size_t)W_ << 5);  // +W pixels = W*256 ushort = W*32 uint4
        const uint4 a = rowA[lane];
        const uint4 bq = rowB[lane];
        unsigned int yp[4];
        float ylo[4], yhi[4];
        #pragma unroll
        for (int d = 0; d < 4; ++d) {
            const unsigned int ua = (&a.x)[d];
            const unsigned int ub = (&bq.x)[d];
            const float alo = h2f((unsigned short)(ua & 0xFFFFu));
            const float ahi = h2f((unsigned short)(ua >> 16));
            const float blo = h2f((unsigned short)(ub & 0xFFFFu));
            const float bhi = h2f((unsigned short)(ub >> 16));
            ylo[d] = alo + dh * (blo - alo);
            yhi[d] = ahi + dh * (bhi - ahi);
            yp[d] = (unsigned)f2h(ylo[d]) | ((unsigned)f2h(yhi[d]) << 16);
        }
        unsigned int xq[4];
        #pragma unroll
        for (int d = 0; d < 4; ++d) xq[d] = (unsigned)__shfl_xor((int)yp[d], 32, 64);
        if (lane < 32) {  // lanes 0-31 hold x0; partner gives x1
            unsigned int wq[4];
            #pragma unroll
            for (int d = 0; d < 4; ++d) {
                const float plo = h2f((unsigned short)(xq[d] & 0xFFFFu));
                const float phi = h2f((unsigned short)(xq[d] >> 16));
                float olo = ylo[d] + dw * (plo - ylo[d]);
                float ohi = yhi[d] + dw * (phi - yhi[d]);
                if (!valid) { olo = 0.0f; ohi = 0.0f; }
                wq[d] = (unsigned)f2h(olo) | ((unsigned)f2h(ohi) << 16);
            }
            // channels 8*lane..8*lane+7 -> pair slots 4*lane..4*lane+3 of row k
            *(uint4*)&shu[k * ROWU + 4 * lane] = make_uint4(wq[0], wq[1], wq[2], wq[3]);
        }
    }
    __syncthreads();

    // copy-out: scalar flat (f = c*49+k), addr k*131+(c>>1): conflict-free (R8)
    float* ob = out + (size_t)r * (C_ * KK);
    #pragma unroll
    for (int i = 0; i < 25; ++i) {
        const int f = threadIdx.x + 512 * i;
        if (i < 24 || f < C_ * KK) {
            const int c = f / KK;
            const int k = f - c * KK;
            const unsigned int u = shu[k * ROWU + (c >> 1)];
            const unsigned short hv = (c & 1) ? (unsigned short)(u >> 16)
                                              : (unsigned short)(u & 0xFFFFu);
            __builtin_nontemporal_store(h2f(hv), &ob[f]);
        }
    }
}

// ---------- Fallback: direct NCHW gather (if ws too small) ----------
__global__ __launch_bounds__(256) void roialign_nchw(
    const float* __restrict__ feat, const float* __restrict__ rois,
    const float* __restrict__ scale_ptr, float* __restrict__ out) {
    __shared__ float sout[C_ * KK];
    const int r = blockIdx.x;
    const int c = threadIdx.x;
    const float scale = scale_ptr[0];
    const float* roi = rois + (size_t)r * 5;
    const int   b  = (int)roi[0];
    const float x1 = roi[1] * scale;
    const float y1 = roi[2] * scale;
    const float x2 = roi[3] * scale;
    const float y2 = roi[4] * scale;
    const float roi_w = fmaxf(x2 - x1 + 1.0f, 0.0f);
    const float roi_h = fmaxf(y2 - y1 + 1.0f, 0.0f);
    const float bin_h = roi_h / (float)(AH - 1);
    const float bin_w = roi_w / (float)(AW - 1);
    const float* fb = feat + ((size_t)b * C_ + c) * (H_ * W_);
    for (int ph = 0; ph < AH; ++ph) {
        const float h  = y1 + (float)ph * bin_h;
        const float hs = fminf(fmaxf(floorf(h), 0.0f), (float)(H_ - 2));
        const float dh = h - hs;
        const int   yi = (int)hs;
        const bool  vh = (h >= 0.0f) && (h < (float)H_);
        #pragma unroll
        for (int pw = 0; pw < AW; ++pw) {
            const float w  = x1 + (float)pw * bin_w;
            const float ws = fminf(fmaxf(floorf(w), 0.0f), (float)(W_ - 2));
            const float dw = w - ws;
            const int   xi = (int)ws;
            const bool  valid = vh && (w >= 0.0f) && (w < (float)W_);
            const float v00 = fb[(size_t)yi * W_ + xi];
            const float v01 = fb[(size_t)yi * W_ + xi + 1];
            const float v10 = fb[(size_t)(yi + 1) * W_ + xi];
            const float v11 = fb[(size_t)(yi + 1) * W_ + xi + 1];
            float val = v00 * (1.0f - dh) * (1.0f - dw)
                      + v01 * (1.0f - dh) * dw
                      + v10 * dh * (1.0f - dw)
                      + v11 * dh * dw;
            sout[c * KK + ph * AW + pw] = valid ? val : 0.0f;
        }
    }
    __syncthreads();
    float* ob = out + (size_t)r * C_ * KK;
    #pragma unroll 4
    for (int i = threadIdx.x; i < C_ * KK; i += 256) ob[i] = sout[i];
}

extern "C" void kernel_launch(void* const* d_in, const int* in_sizes, int n_in,
                              void* d_out, int out_size, void* d_ws, size_t ws_size,
                              hipStream_t stream) {
    const float* feat  = (const float*)d_in[0];
    const float* rois  = (const float*)d_in[1];
    const float* scale = (const float*)d_in[2];
    float* out = (float*)d_out;

    const int R = in_sizes[1] / 5;                 // 2000
    const int N = in_sizes[0] / (C_ * H_ * W_);    // 2
    const size_t need = (size_t)N * C_ * H_ * W_ * sizeof(unsigned short);

    if (ws_size >= need) {
        unsigned short* tf = (unsigned short*)d_ws;
        dim3 tb(256);
        dim3 tg((H_ * W_) / 64, C_ / 128, N);      // 950 x 2 x 2
        hipLaunchKernelGGL(transpose_nchw_nhwc_f16, tg, tb, 0, stream, feat, tf);
        hipLaunchKernelGGL(roialign_nhwc_f16, dim3(R), dim3(512), 0, stream,
                           tf, rois, scale, out);
    } else {
        hipLaunchKernelGGL(roialign_nchw, dim3(R), dim3(256), 0, stream,
                           feat, rois, scale, out);
    }
}

// Round 11
// 78.944 us; speedup vs baseline: 2.4938x; 1.0654x over previous
//
#include <hip/hip_runtime.h>

// RoIAlign (aligned-corner variant), fixed shape:
//   features: (N=2, C=256, H=200, W=304) f32 NCHW, rois: (R,5) f32, scale f32
//   out: (R, 256, 7, 7) f32
// Pipeline: NCHW f32 -> NHWC f16 transpose (ws, HBM-roofline), then gather
// with packed-f16 LDS staging [k][131 u32] (25.7KB -> 4 blocks/CU).
// == R8 configuration: best measured (79.0us). R9 coop-fusion (-149%) and
// R10 row-load restructure (-6%) both regressed; this is the keeper. ==
#define C_ 256
#define H_ 200
#define W_ 304
#define AH 7
#define AW 7
#define KK 49
#define ROWU 131  // u32 per LDS row; stride 131 = 3 mod 32 -> conflict-free scalar copy-out

typedef float f32x4 __attribute__((ext_vector_type(4)));

__device__ __forceinline__ float h2f(unsigned short s) {
    _Float16 h; __builtin_memcpy(&h, &s, 2); return (float)h;
}
__device__ __forceinline__ unsigned short f2h(float f) {
    _Float16 h = (_Float16)f; unsigned short s; __builtin_memcpy(&s, &h, 2); return s;
}

// ---------- Kernel 1: NCHW f32 -> NHWC f16 (measured 6.2 TB/s, at copy ceiling) ----------
__global__ __launch_bounds__(256) void transpose_nchw_nhwc_f16(
    const float* __restrict__ in, unsigned short* __restrict__ out) {
    __shared__ unsigned int tile[128][34];  // [ch][px-pair], 17408 B
    const int HW = H_ * W_;
    const int n  = blockIdx.z;
    const int p0 = blockIdx.x * 64;
    const int c0 = blockIdx.y * 128;
    const float* inb = in + (size_t)n * C_ * HW;
    unsigned short* outb = out + (size_t)n * HW * C_;

    {   // load: lanes walk pixel-quads, convert f32->f16 before LDS
        const int q  = threadIdx.x & 15;
        const int r0 = threadIdx.x >> 4;
        #pragma unroll
        for (int i = 0; i < 8; ++i) {
            const int c = r0 + 16 * i;
            const f32x4 v = __builtin_nontemporal_load(
                (const f32x4*)&inb[(size_t)(c0 + c) * HW + p0 + 4 * q]);
            const unsigned int ulo = (unsigned)f2h(v.x) | ((unsigned)f2h(v.y) << 16);
            const unsigned int uhi = (unsigned)f2h(v.z) | ((unsigned)f2h(v.w) << 16);
            *(uint2*)&tile[c][2 * q] = make_uint2(ulo, uhi);
        }
    }
    __syncthreads();
    {   // store: repack pixel-pairs -> channel-contiguous ushort8 (16B/lane)
        const int pp0 = threadIdx.x & 15;
        const int cq  = threadIdx.x >> 4;
        #pragma unroll
        for (int i = 0; i < 2; ++i) {
            const int pp = pp0 + 16 * i;
            unsigned int u[8];
            #pragma unroll
            for (int jj = 0; jj < 8; ++jj) u[jj] = tile[8 * cq + jj][pp];
            unsigned int pe[4], po[4];
            #pragma unroll
            for (int k = 0; k < 4; ++k) {
                pe[k] = (u[2 * k] & 0xFFFFu) | (u[2 * k + 1] << 16);
                po[k] = (u[2 * k] >> 16) | (u[2 * k + 1] & 0xFFFF0000u);
            }
            unsigned short* oA = &outb[(size_t)(p0 + 2 * pp) * C_ + c0 + 8 * cq];
            unsigned short* oB = oA + C_;
            *(uint4*)oA = make_uint4(pe[0], pe[1], pe[2], pe[3]);
            *(uint4*)oB = make_uint4(po[0], po[1], po[2], po[3]);
        }
    }
}

// ---------- sample one (roi, point) across 4 channels ----------
__device__ __forceinline__ void samp(
    const unsigned short* __restrict__ fb, int k,
    float y1, float x1, float bin_h, float bin_w, int c4, float* o) {
    const int ph = k / AW;
    const int pw = k - ph * AW;
    const float h  = y1 + (float)ph * bin_h;
    const float w  = x1 + (float)pw * bin_w;
    const float hs = fminf(fmaxf(floorf(h), 0.0f), (float)(H_ - 2));
    const float ws = fminf(fmaxf(floorf(w), 0.0f), (float)(W_ - 2));
    const float dh = h - hs;
    const float dw = w - ws;
    const int   yi = (int)hs;
    const int   xi = (int)ws;
    const bool  valid = (h >= 0.0f) && (h < (float)H_) &&
                        (w >= 0.0f) && (w < (float)W_);
    const unsigned short* p = fb + ((size_t)yi * W_ + xi) * C_ + c4;
    const ushort4 a00 = *(const ushort4*)p;
    const ushort4 a01 = *(const ushort4*)(p + C_);
    const ushort4 a10 = *(const ushort4*)(p + (size_t)W_ * C_);
    const ushort4 a11 = *(const ushort4*)(p + (size_t)W_ * C_ + C_);
    const float w00 = (1.0f - dh) * (1.0f - dw);
    const float w01 = (1.0f - dh) * dw;
    const float w10 = dh * (1.0f - dw);
    const float w11 = dh * dw;
    o[0] = h2f(a00.x) * w00 + h2f(a01.x) * w01 + h2f(a10.x) * w10 + h2f(a11.x) * w11;
    o[1] = h2f(a00.y) * w00 + h2f(a01.y) * w01 + h2f(a10.y) * w10 + h2f(a11.y) * w11;
    o[2] = h2f(a00.z) * w00 + h2f(a01.z) * w01 + h2f(a10.z) * w10 + h2f(a11.z) * w11;
    o[3] = h2f(a00.w) * w00 + h2f(a01.w) * w01 + h2f(a10.w) * w10 + h2f(a11.w) * w11;
    if (!valid) { o[0] = 0.0f; o[1] = 0.0f; o[2] = 0.0f; o[3] = 0.0f; }
}

// ---------- Kernel 2: gather from NHWC f16, packed-f16 LDS staging ----------
// 512 thr = 8 waves per ROI. Wave w: points k = w, w+8, ...
// Lane owns 4 channels (ushort4 8B corner loads, 512B/corner/wave coalesced).
// LDS: u32 shu[49][ROWU]; row k holds 128 c-pairs at [2*lane], [2*lane+1].
// Copy-out: scalar flat (f = c*49+k), addr k*131+(c>>1): stride 3 mod 32 ->
// conflict-free; scalar nontemporal dword stores (256B/wave-instr).
__global__ __launch_bounds__(512) void roialign_nhwc_f16(
    const unsigned short* __restrict__ tf, const float* __restrict__ rois,
    const float* __restrict__ scale_ptr, float* __restrict__ out) {
    __shared__ unsigned int shu[KK * ROWU];  // 25676 B -> 4 blocks/CU (thread-cap)
    const int r    = blockIdx.x;
    const int wave = threadIdx.x >> 6;
    const int lane = threadIdx.x & 63;
    const int c4   = lane * 4;

    const float scale = scale_ptr[0];
    const float* roi = rois + (size_t)r * 5;
    const int   b  = (int)roi[0];
    const float x1 = roi[1] * scale;
    const float y1 = roi[2] * scale;
    const float x2 = roi[3] * scale;
    const float y2 = roi[4] * scale;
    const float roi_w = fmaxf(x2 - x1 + 1.0f, 0.0f);
    const float roi_h = fmaxf(y2 - y1 + 1.0f, 0.0f);
    const float bin_h = roi_h / (float)(AH - 1);
    const float bin_w = roi_w / (float)(AW - 1);
    const unsigned short* fb = tf + (size_t)b * (H_ * W_) * C_;

    #pragma unroll 2
    for (int k = wave; k < KK; k += 8) {
        float v[4];
        samp(fb, k, y1, x1, bin_h, bin_w, c4, v);
        const unsigned int u0 = (unsigned)f2h(v[0]) | ((unsigned)f2h(v[1]) << 16);
        const unsigned int u1 = (unsigned)f2h(v[2]) | ((unsigned)f2h(v[3]) << 16);
        shu[k * ROWU + 2 * lane]     = u0;
        shu[k * ROWU + 2 * lane + 1] = u1;
    }
    __syncthreads();

    float* ob = out + (size_t)r * (C_ * KK);
    #pragma unroll
    for (int i = 0; i < 25; ++i) {
        const int f = threadIdx.x + 512 * i;
        if (i < 24 || f < C_ * KK) {
            const int c = f / KK;          // magic-mul
            const int k = f - c * KK;
            const unsigned int u = shu[k * ROWU + (c >> 1)];
            const unsigned short hv = (c & 1) ? (unsigned short)(u >> 16)
                                              : (unsigned short)(u & 0xFFFFu);
            __builtin_nontemporal_store(h2f(hv), &ob[f]);
        }
    }
}

// ---------- Fallback: direct NCHW gather (if ws too small) ----------
__global__ __launch_bounds__(256) void roialign_nchw(
    const float* __restrict__ feat, const float* __restrict__ rois,
    const float* __restrict__ scale_ptr, float* __restrict__ out) {
    __shared__ float sout[C_ * KK];
    const int r = blockIdx.x;
    const int c = threadIdx.x;
    const float scale = scale_ptr[0];
    const float* roi = rois + (size_t)r * 5;
    const int   b  = (int)roi[0];
    const float x1 = roi[1] * scale;
    const float y1 = roi[2] * scale;
    const float x2 = roi[3] * scale;
    const float y2 = roi[4] * scale;
    const float roi_w = fmaxf(x2 - x1 + 1.0f, 0.0f);
    const float roi_h = fmaxf(y2 - y1 + 1.0f, 0.0f);
    const float bin_h = roi_h / (float)(AH - 1);
    const float bin_w = roi_w / (float)(AW - 1);
    const float* fb = feat + ((size_t)b * C_ + c) * (H_ * W_);

    for (int ph = 0; ph < AH; ++ph) {
        const float h  = y1 + (float)ph * bin_h;
        const float hs = fminf(fmaxf(floorf(h), 0.0f), (float)(H_ - 2));
        const float dh = h - hs;
        const int   yi = (int)hs;
        const bool  vh = (h >= 0.0f) && (h < (float)H_);
        #pragma unroll
        for (int pw = 0; pw < AW; ++pw) {
            const float w  = x1 + (float)pw * bin_w;
            const float ws = fminf(fmaxf(floorf(w), 0.0f), (float)(W_ - 2));
            const float dw = w - ws;
            const int   xi = (int)ws;
            const bool  valid = vh && (w >= 0.0f) && (w < (float)W_);
            const float v00 = fb[(size_t)yi * W_ + xi];
            const float v01 = fb[(size_t)yi * W_ + xi + 1];
            const float v10 = fb[(size_t)(yi + 1) * W_ + xi];
            const float v11 = fb[(size_t)(yi + 1) * W_ + xi + 1];
            float val = v00 * (1.0f - dh) * (1.0f - dw)
                      + v01 * (1.0f - dh) * dw
                      + v10 * dh * (1.0f - dw)
                      + v11 * dh * dw;
            sout[c * KK + ph * AW + pw] = valid ? val : 0.0f;
        }
    }
    __syncthreads();
    float* ob = out + (size_t)r * C_ * KK;
    #pragma unroll 4
    for (int i = threadIdx.x; i < C_ * KK; i += 256) ob[i] = sout[i];
}

extern "C" void kernel_launch(void* const* d_in, const int* in_sizes, int n_in,
                              void* d_out, int out_size, void* d_ws, size_t ws_size,
                              hipStream_t stream) {
    const float* feat  = (const float*)d_in[0];
    const float* rois  = (const float*)d_in[1];
    const float* scale = (const float*)d_in[2];
    float* out = (float*)d_out;

    const int R = in_sizes[1] / 5;                 // 2000
    const int N = in_sizes[0] / (C_ * H_ * W_);    // 2
    const size_t need = (size_t)N * C_ * H_ * W_ * sizeof(unsigned short);

    if (ws_size >= need) {
        unsigned short* tf = (unsigned short*)d_ws;
        dim3 tb(256);
        dim3 tg((H_ * W_) / 64, C_ / 128, N);      // 950 x 2 x 2
        hipLaunchKernelGGL(transpose_nchw_nhwc_f16, tg, tb, 0, stream, feat, tf);
        hipLaunchKernelGGL(roialign_nhwc_f16, dim3(R), dim3(512), 0, stream,
                           tf, rois, scale, out);
    } else {
        hipLaunchKernelGGL(roialign_nchw, dim3(R), dim3(256), 0, stream,
                           feat, rois, scale, out);
    }
}